// Round 6
// baseline (1217.873 us; speedup 1.0000x reference)
//
#include <hip/hip_runtime.h>

#define N_NODES 50000
#define N_EDGES 400000
#define D 512
#define NCLS 40
#define SCAN_BLOCKS ((N_NODES + 255) / 256)
#define N_TILES ((N_NODES + 31) / 32)   // 1563
#define ZSTRIDE 520                     // 512 + 8 elem pad (16B) for LDS bank spread

typedef __attribute__((ext_vector_type(8))) __bf16 bf16x8;
typedef __attribute__((ext_vector_type(4))) float f32x4;
typedef __attribute__((ext_vector_type(4))) float float4v;
typedef __attribute__((ext_vector_type(8))) unsigned short ushort8v;
typedef __attribute__((ext_vector_type(4))) unsigned short ushort4v;

__device__ __forceinline__ float bf2f(unsigned short u) {
  union { unsigned int i; float f; } v; v.i = ((unsigned int)u) << 16; return v.f;
}
__device__ __forceinline__ unsigned short f2bf(float f) {
  union { float f; unsigned int i; } v; v.f = f;
  unsigned int u = v.i;
  u += 0x7fffu + ((u >> 16) & 1u);  // round-nearest-even
  return (unsigned short)(u >> 16);
}

// ---------------- CSR build ----------------
__global__ void hist_kernel(const int* __restrict__ dst, int* __restrict__ counts) {
  int e = blockIdx.x * blockDim.x + threadIdx.x;
  if (e < N_EDGES) atomicAdd(&counts[dst[e]], 1);
}

__global__ __launch_bounds__(256) void scan_local_kernel(const int* __restrict__ counts,
    int* __restrict__ incl, int* __restrict__ bsum) {
  __shared__ int s[256];
  int i = blockIdx.x * 256 + threadIdx.x;
  int v = (i < N_NODES) ? counts[i] : 0;
  s[threadIdx.x] = v;
  __syncthreads();
#pragma unroll
  for (int o = 1; o < 256; o <<= 1) {
    int t = (threadIdx.x >= o) ? s[threadIdx.x - o] : 0;
    __syncthreads();
    s[threadIdx.x] += t;
    __syncthreads();
  }
  if (i < N_NODES) incl[i] = s[threadIdx.x];
  if (threadIdx.x == 255) bsum[blockIdx.x] = s[255];
}

__global__ __launch_bounds__(256) void scan_bsum_kernel(int* __restrict__ bsum) {
  __shared__ int s[256];
  int v = (threadIdx.x < SCAN_BLOCKS) ? bsum[threadIdx.x] : 0;
  s[threadIdx.x] = v;
  __syncthreads();
#pragma unroll
  for (int o = 1; o < 256; o <<= 1) {
    int t = (threadIdx.x >= o) ? s[threadIdx.x - o] : 0;
    __syncthreads();
    s[threadIdx.x] += t;
    __syncthreads();
  }
  if (threadIdx.x < SCAN_BLOCKS) bsum[threadIdx.x] = s[threadIdx.x] - v;  // exclusive
}

__global__ __launch_bounds__(256) void scan_finish_kernel(const int* __restrict__ counts,
    const int* __restrict__ bsum, int* __restrict__ row_ptr, int* __restrict__ cursor) {
  int i = blockIdx.x * 256 + threadIdx.x;
  if (i < N_NODES) {
    int inc = cursor[i] + bsum[blockIdx.x];
    row_ptr[i + 1] = inc;
    cursor[i] = inc - counts[i];
    if (i == 0) row_ptr[0] = 0;
  }
}

__global__ void fill_kernel(const int* __restrict__ src, const int* __restrict__ dst,
                            int* __restrict__ cursor, int* __restrict__ esrc) {
  int e = blockIdx.x * blockDim.x + threadIdx.x;
  if (e < N_EDGES) {
    int pos = atomicAdd(&cursor[dst[e]], 1);
    esrc[pos] = src[e];
  }
}

// ---------------- conversions ----------------
__global__ void cvt_feat_kernel(const float* __restrict__ feat, unsigned short* __restrict__ hb) {
  size_t i = (size_t)(blockIdx.x * blockDim.x + threadIdx.x) * 4;
  if (i < (size_t)N_NODES * D) {
    float4v v = *(const float4v*)&feat[i];
    ushort4v o;
    o[0] = f2bf(v[0]); o[1] = f2bf(v[1]); o[2] = f2bf(v[2]); o[3] = f2bf(v[3]);
    *(ushort4v*)&hb[i] = o;
  }
}

// Wt[n*512 + k] = bf16(W[k*512 + n])
__global__ void cvt_w_kernel(const float* __restrict__ W, unsigned short* __restrict__ Wt) {
  int i = blockIdx.x * blockDim.x + threadIdx.x;
  int n = i >> 9, k = i & 511;
  Wt[i] = f2bf(W[k * D + n]);
}

// Wct[n*512 + k] = bf16(Wc[k*40 + n]) for n<40, else 0
__global__ void cvt_wc_kernel(const float* __restrict__ Wc, unsigned short* __restrict__ Wct) {
  int i = blockIdx.x * blockDim.x + threadIdx.x;
  if (i < 48 * D) {
    int n = i >> 9, k = i & 511;
    Wct[i] = (n < NCLS) ? f2bf(Wc[k * NCLS + n]) : (unsigned short)0;
  }
}

// ---------------- fused layer: Hout = relu((Hin + gather-sum) @ W + b) ----------------
// BM=32 node tile. Phase 1: 4 waves aggregate 8 nodes each into LDS z-tile (fp32 acc,
// bf16 store, stride 520). Phase 2: barrier-free K-loop — a-frags from LDS (loaded
// once), b-frags direct from L2-resident Wt; wave w covers n in [w*128, w*128+128).
// Epilogue stages C through LDS for full-line coalesced stores. Work-stealing over
// 1563 tiles. 4 blocks/CU (LDS 33.3KB, VGPR<=128) so gather/MFMA phases of different
// blocks overlap on a CU.
__global__ __launch_bounds__(256, 4) void fused_kernel(
    const unsigned short* __restrict__ Hin, const int* __restrict__ row_ptr,
    const int* __restrict__ esrc, const unsigned short* __restrict__ Wt,
    const float* __restrict__ bias, unsigned short* __restrict__ Hout,
    int* __restrict__ counter) {
  __shared__ unsigned short Zs[32 * ZSTRIDE];  // 33.3 KB; z-tile then C-tile
  __shared__ int tile_s;
  const int tid = threadIdx.x;
  const int lane = tid & 63;
  const int w = tid >> 6;
  const int quad = lane >> 4, r16 = lane & 15;
  const int col = lane * 8;

  for (;;) {
    if (tid == 0) tile_s = atomicAdd(counter, 1);
    __syncthreads();
    const int tile = tile_s;
    if (tile >= N_TILES) break;
    const int m0 = tile * 32;

    // ---- phase 1: aggregate 32 node rows into Zs
    for (int i = 0; i < 8; ++i) {
      int nl = w * 8 + i;
      int node = m0 + nl;
      float acc[8];
      if (node < N_NODES) {
        ushort8v v = *(const ushort8v*)&Hin[(size_t)node * D + col];
#pragma unroll
        for (int t = 0; t < 8; ++t) acc[t] = bf2f(v[t]);
        int s = row_ptr[node], e = row_ptr[node + 1];
        int j = s;
        for (; j + 4 <= e; j += 4) {
          int i0 = esrc[j + 0], i1 = esrc[j + 1], i2 = esrc[j + 2], i3 = esrc[j + 3];
          ushort8v v0 = *(const ushort8v*)&Hin[(size_t)i0 * D + col];
          ushort8v v1 = *(const ushort8v*)&Hin[(size_t)i1 * D + col];
          ushort8v v2 = *(const ushort8v*)&Hin[(size_t)i2 * D + col];
          ushort8v v3 = *(const ushort8v*)&Hin[(size_t)i3 * D + col];
#pragma unroll
          for (int t = 0; t < 8; ++t) acc[t] += bf2f(v0[t]);
#pragma unroll
          for (int t = 0; t < 8; ++t) acc[t] += bf2f(v1[t]);
#pragma unroll
          for (int t = 0; t < 8; ++t) acc[t] += bf2f(v2[t]);
#pragma unroll
          for (int t = 0; t < 8; ++t) acc[t] += bf2f(v3[t]);
        }
        for (; j < e; ++j) {
          int sn = esrc[j];
          ushort8v nv = *(const ushort8v*)&Hin[(size_t)sn * D + col];
#pragma unroll
          for (int t = 0; t < 8; ++t) acc[t] += bf2f(nv[t]);
        }
      } else {
#pragma unroll
        for (int t = 0; t < 8; ++t) acc[t] = 0.f;
      }
      ushort8v o;
#pragma unroll
      for (int t = 0; t < 8; ++t) o[t] = f2bf(acc[t]);
      *(ushort8v*)&Zs[nl * ZSTRIDE + col] = o;
    }
    __syncthreads();

    // ---- phase 2: GEMM 32x512 (barrier-free K-loop)
    const int wn = w * 128;
    f32x4 c[2][8];
#pragma unroll
    for (int i = 0; i < 2; ++i)
#pragma unroll
      for (int j = 0; j < 8; ++j) c[i][j] = (f32x4){0.f, 0.f, 0.f, 0.f};
#pragma unroll
    for (int kt = 0; kt < 16; ++kt) {
      int kk = kt * 32 + quad * 8;
      bf16x8 a0 = *(const bf16x8*)&Zs[r16 * ZSTRIDE + kk];
      bf16x8 a1 = *(const bf16x8*)&Zs[(16 + r16) * ZSTRIDE + kk];
#pragma unroll
      for (int j = 0; j < 8; ++j) {
        bf16x8 b = *(const bf16x8*)&Wt[(size_t)(wn + j * 16 + r16) * D + kk];
        c[0][j] = __builtin_amdgcn_mfma_f32_16x16x32_bf16(a0, b, c[0][j], 0, 0, 0);
        c[1][j] = __builtin_amdgcn_mfma_f32_16x16x32_bf16(a1, b, c[1][j], 0, 0, 0);
      }
    }
    __syncthreads();  // all a-frag reads done before Zs reused as C-tile

    // ---- epilogue: bias+relu -> Cs (reuse Zs) -> coalesced store
#pragma unroll
    for (int j = 0; j < 8; ++j) {
      float bv = bias[wn + j * 16 + r16];
#pragma unroll
      for (int i = 0; i < 2; ++i) {
        int crow = i * 16 + quad * 4;
#pragma unroll
        for (int r = 0; r < 4; ++r) {
          float vv = c[i][j][r] + bv;
          vv = vv > 0.f ? vv : 0.f;
          Zs[(crow + r) * ZSTRIDE + wn + j * 16 + r16] = f2bf(vv);
        }
      }
    }
    __syncthreads();
#pragma unroll
    for (int i = 0; i < 8; ++i) {
      int row = w * 8 + i;
      int gm = m0 + row;
      if (gm < N_NODES) {
        ushort8v vv = *(const ushort8v*)&Zs[row * ZSTRIDE + col];
        __builtin_nontemporal_store(vv, (ushort8v*)&Hout[(size_t)gm * D + col]);
      }
    }
    __syncthreads();  // protect Zs/tile_s for next tile
  }
}

// ---------------- classifier: out = h3 @ Wc + bc  (bf16 MFMA, no LDS) ----------------
__global__ __launch_bounds__(256) void cls_kernel(const unsigned short* __restrict__ hb,
    const unsigned short* __restrict__ Wct, const float* __restrict__ bc,
    float* __restrict__ out) {
  int w = threadIdx.x >> 6, lane = threadIdx.x & 63;
  int quad = lane >> 4, r16 = lane & 15;
  int nb = blockIdx.x * 64 + w * 16;
  int arow = nb + r16; if (arow > N_NODES - 1) arow = N_NODES - 1;
  f32x4 acc[3];
#pragma unroll
  for (int j = 0; j < 3; ++j) acc[j] = (f32x4){0.f, 0.f, 0.f, 0.f};
#pragma unroll 4
  for (int kt = 0; kt < 16; ++kt) {
    int kk = kt * 32 + quad * 8;
    bf16x8 a = *(const bf16x8*)&hb[(size_t)arow * D + kk];
#pragma unroll
    for (int j = 0; j < 3; ++j) {
      bf16x8 b = *(const bf16x8*)&Wct[(size_t)(j * 16 + r16) * D + kk];
      acc[j] = __builtin_amdgcn_mfma_f32_16x16x32_bf16(a, b, acc[j], 0, 0, 0);
    }
  }
#pragma unroll
  for (int j = 0; j < 3; ++j) {
    int gn = j * 16 + r16;
    if (gn < NCLS) {
      float bv = bc[gn];
#pragma unroll
      for (int r = 0; r < 4; ++r) {
        int gm = nb + quad * 4 + r;
        if (gm < N_NODES) out[(size_t)gm * NCLS + gn] = acc[j][r] + bv;
      }
    }
  }
}

extern "C" void kernel_launch(void* const* d_in, const int* in_sizes, int n_in,
                              void* d_out, int out_size, void* d_ws, size_t ws_size,
                              hipStream_t stream) {
  const float* feat = (const float*)d_in[0];
  const int* src = (const int*)d_in[1];
  const int* dst = (const int*)d_in[2];
  const float* W0 = (const float*)d_in[3];
  const float* b0 = (const float*)d_in[4];
  const float* W1 = (const float*)d_in[5];
  const float* b1 = (const float*)d_in[6];
  const float* W2 = (const float*)d_in[7];
  const float* b2 = (const float*)d_in[8];
  const float* Wc = (const float*)d_in[9];
  const float* bc = (const float*)d_in[10];
  float* out = (float*)d_out;

  char* ws = (char*)d_ws;
  size_t off = 0;
  auto alloc = [&](size_t bytes) {
    char* p = ws + off;
    off += (bytes + 255) & ~(size_t)255;
    return p;
  };
  unsigned short* hb = (unsigned short*)alloc((size_t)N_NODES * D * 2);   // 51.2 MB
  unsigned short* zb = (unsigned short*)alloc((size_t)N_NODES * D * 2);   // 51.2 MB (ping-pong)
  unsigned short* Wt = (unsigned short*)alloc((size_t)3 * D * D * 2);     // 1.5 MB
  unsigned short* Wct = (unsigned short*)alloc((size_t)48 * D * 2);       // 49 KB
  int* row_ptr = (int*)alloc((size_t)(N_NODES + 1) * 4);
  int* counts  = (int*)alloc((size_t)N_NODES * 4);
  int* cursor  = (int*)alloc((size_t)N_NODES * 4);
  int* esrc    = (int*)alloc((size_t)N_EDGES * 4);
  int* bsum    = (int*)alloc((size_t)256 * 4);
  int* ctrs    = (int*)alloc((size_t)4 * 4);   // work-steal counters (one per layer)

  // CSR build
  hipMemsetAsync(counts, 0, (size_t)N_NODES * 4, stream);
  hipMemsetAsync(ctrs, 0, 16, stream);
  hist_kernel<<<(N_EDGES + 255) / 256, 256, 0, stream>>>(dst, counts);
  scan_local_kernel<<<SCAN_BLOCKS, 256, 0, stream>>>(counts, cursor, bsum);
  scan_bsum_kernel<<<1, 256, 0, stream>>>(bsum);
  scan_finish_kernel<<<SCAN_BLOCKS, 256, 0, stream>>>(counts, bsum, row_ptr, cursor);
  fill_kernel<<<(N_EDGES + 255) / 256, 256, 0, stream>>>(src, dst, cursor, esrc);

  cvt_feat_kernel<<<(N_NODES * D / 4 + 255) / 256, 256, 0, stream>>>(feat, hb);
  cvt_w_kernel<<<1024, 256, 0, stream>>>(W0, Wt);
  cvt_w_kernel<<<1024, 256, 0, stream>>>(W1, Wt + (size_t)D * D);
  cvt_w_kernel<<<1024, 256, 0, stream>>>(W2, Wt + (size_t)2 * D * D);
  cvt_wc_kernel<<<(48 * D + 255) / 256, 256, 0, stream>>>(Wc, Wct);

  // fused layers, ping-pong hb <-> zb
  const float* bs[3] = {b0, b1, b2};
  unsigned short* bufs[2] = {hb, zb};
  for (int l = 0; l < 3; ++l) {
    fused_kernel<<<1024, 256, 0, stream>>>(bufs[l & 1], row_ptr, esrc,
        Wt + (size_t)l * D * D, bs[l], bufs[(l + 1) & 1], ctrs + l);
  }
  cls_kernel<<<(N_NODES + 63) / 64, 256, 0, stream>>>(zb, Wct, bc, out);
}

// Round 7
// 627.603 us; speedup vs baseline: 1.9405x; 1.9405x over previous
//
#include <hip/hip_runtime.h>

#define N_NODES 50000
#define N_EDGES 400000
#define D 512
#define NCLS 40
#define SCAN_BLOCKS ((N_NODES + 255) / 256)

typedef __attribute__((ext_vector_type(8))) __bf16 bf16x8;
typedef __attribute__((ext_vector_type(4))) float f32x4;
typedef __attribute__((ext_vector_type(4))) float float4v;
typedef __attribute__((ext_vector_type(8))) unsigned short ushort8v;
typedef __attribute__((ext_vector_type(4))) unsigned short ushort4v;

#define AS1 __attribute__((address_space(1)))
#define AS3 __attribute__((address_space(3)))

__device__ __forceinline__ float bf2f(unsigned short u) {
  union { unsigned int i; float f; } v; v.i = ((unsigned int)u) << 16; return v.f;
}
__device__ __forceinline__ unsigned short f2bf(float f) {
  union { float f; unsigned int i; } v; v.f = f;
  unsigned int u = v.i;
  u += 0x7fffu + ((u >> 16) & 1u);  // round-nearest-even
  return (unsigned short)(u >> 16);
}

// ---------------- CSR build ----------------
__global__ void hist_kernel(const int* __restrict__ dst, int* __restrict__ counts) {
  int e = blockIdx.x * blockDim.x + threadIdx.x;
  if (e < N_EDGES) atomicAdd(&counts[dst[e]], 1);
}

__global__ __launch_bounds__(256) void scan_local_kernel(const int* __restrict__ counts,
    int* __restrict__ incl, int* __restrict__ bsum) {
  __shared__ int s[256];
  int i = blockIdx.x * 256 + threadIdx.x;
  int v = (i < N_NODES) ? counts[i] : 0;
  s[threadIdx.x] = v;
  __syncthreads();
#pragma unroll
  for (int o = 1; o < 256; o <<= 1) {
    int t = (threadIdx.x >= o) ? s[threadIdx.x - o] : 0;
    __syncthreads();
    s[threadIdx.x] += t;
    __syncthreads();
  }
  if (i < N_NODES) incl[i] = s[threadIdx.x];
  if (threadIdx.x == 255) bsum[blockIdx.x] = s[255];
}

__global__ __launch_bounds__(256) void scan_bsum_kernel(int* __restrict__ bsum) {
  __shared__ int s[256];
  int v = (threadIdx.x < SCAN_BLOCKS) ? bsum[threadIdx.x] : 0;
  s[threadIdx.x] = v;
  __syncthreads();
#pragma unroll
  for (int o = 1; o < 256; o <<= 1) {
    int t = (threadIdx.x >= o) ? s[threadIdx.x - o] : 0;
    __syncthreads();
    s[threadIdx.x] += t;
    __syncthreads();
  }
  if (threadIdx.x < SCAN_BLOCKS) bsum[threadIdx.x] = s[threadIdx.x] - v;  // exclusive
}

__global__ __launch_bounds__(256) void scan_finish_kernel(const int* __restrict__ counts,
    const int* __restrict__ bsum, int* __restrict__ row_ptr, int* __restrict__ cursor) {
  int i = blockIdx.x * 256 + threadIdx.x;
  if (i < N_NODES) {
    int inc = cursor[i] + bsum[blockIdx.x];
    row_ptr[i + 1] = inc;
    cursor[i] = inc - counts[i];
    if (i == 0) row_ptr[0] = 0;
  }
}

__global__ void fill_kernel(const int* __restrict__ src, const int* __restrict__ dst,
                            int* __restrict__ cursor, int* __restrict__ esrc) {
  int e = blockIdx.x * blockDim.x + threadIdx.x;
  if (e < N_EDGES) {
    int pos = atomicAdd(&cursor[dst[e]], 1);
    esrc[pos] = src[e];
  }
}

// ---------------- conversions ----------------
__global__ void cvt_feat_kernel(const float* __restrict__ feat, unsigned short* __restrict__ hb) {
  size_t i = (size_t)(blockIdx.x * blockDim.x + threadIdx.x) * 4;
  if (i < (size_t)N_NODES * D) {
    float4v v = *(const float4v*)&feat[i];
    ushort4v o;
    o[0] = f2bf(v[0]); o[1] = f2bf(v[1]); o[2] = f2bf(v[2]); o[3] = f2bf(v[3]);
    *(ushort4v*)&hb[i] = o;
  }
}

// All 3 weights in one launch: Wt[l][n*512+k] = bf16(Wl[k*512+n])
__global__ void cvt_w3_kernel(const float* __restrict__ W0, const float* __restrict__ W1,
                              const float* __restrict__ W2, unsigned short* __restrict__ Wt) {
  int i = blockIdx.x * blockDim.x + threadIdx.x;   // < 3*262144
  int l = i >> 18;
  int r = i & 262143;
  int n = r >> 9, k = r & 511;
  const float* W = (l == 0) ? W0 : ((l == 1) ? W1 : W2);
  Wt[i] = f2bf(W[k * D + n]);
}

// Wct[n*512 + k] = bf16(Wc[k*40 + n]) for n<40, else 0
__global__ void cvt_wc_kernel(const float* __restrict__ Wc, unsigned short* __restrict__ Wct) {
  int i = blockIdx.x * blockDim.x + threadIdx.x;
  if (i < 48 * D) {
    int n = i >> 9, k = i & 511;
    Wct[i] = (n < NCLS) ? f2bf(Wc[k * NCLS + n]) : (unsigned short)0;
  }
}

// ---------------- aggregation: z = h + sum_{e: dst=i} h[src[e]] ----------------
// One wave per node (max TLP — round-6 lesson: do not serialize gathers per wave).
__global__ __launch_bounds__(256) void agg_kernel(const unsigned short* __restrict__ hb,
    const int* __restrict__ row_ptr, const int* __restrict__ esrc,
    unsigned short* __restrict__ zb) {
  int w = threadIdx.x >> 6, lane = threadIdx.x & 63;
  int node = blockIdx.x * 4 + w;
  int col = lane * 8;
  const unsigned short* hcol = hb + col;
  float acc[8];
  ushort8v v = *(const ushort8v*)&hcol[(size_t)node * D];
#pragma unroll
  for (int t = 0; t < 8; ++t) acc[t] = bf2f(v[t]);
  int s = row_ptr[node], e = row_ptr[node + 1];
  int j = s;
  for (; j + 4 <= e; j += 4) {
    int i0 = esrc[j + 0], i1 = esrc[j + 1], i2 = esrc[j + 2], i3 = esrc[j + 3];
    ushort8v v0 = *(const ushort8v*)&hcol[(size_t)i0 * D];
    ushort8v v1 = *(const ushort8v*)&hcol[(size_t)i1 * D];
    ushort8v v2 = *(const ushort8v*)&hcol[(size_t)i2 * D];
    ushort8v v3 = *(const ushort8v*)&hcol[(size_t)i3 * D];
#pragma unroll
    for (int t = 0; t < 8; ++t) acc[t] += bf2f(v0[t]);
#pragma unroll
    for (int t = 0; t < 8; ++t) acc[t] += bf2f(v1[t]);
#pragma unroll
    for (int t = 0; t < 8; ++t) acc[t] += bf2f(v2[t]);
#pragma unroll
    for (int t = 0; t < 8; ++t) acc[t] += bf2f(v3[t]);
  }
  for (; j < e; ++j) {
    int sn = esrc[j];
    ushort8v nv = *(const ushort8v*)&hcol[(size_t)sn * D];
#pragma unroll
    for (int t = 0; t < 8; ++t) acc[t] += bf2f(nv[t]);
  }
  ushort8v o;
#pragma unroll
  for (int t = 0; t < 8; ++t) o[t] = f2bf(acc[t]);
  *(ushort8v*)&zb[(size_t)node * D + col] = o;
}

// ---------------- GEMM: Hout = relu(Z @ W + b), bf16 MFMA ----------------
// 128x128 tile, BK=64 (8 K-iterations -> half the barrier drains of BK=32).
// LDS layout [row][64k] with XOR-swizzled 16B chunks: chunk slot j of row r holds
// global chunk j^(r&7). Swizzle is applied on the GLOBAL address side of
// global_load_lds (LDS dest must stay lane-linear); frag reads then hit all 32
// banks at exactly 2 lanes/bank (free) -> no ds_read bank conflicts.
// Epilogue stages C through LDS (stride 132) for full-line coalesced stores.
__global__ __launch_bounds__(256) void gemm_kernel(
    const unsigned short* __restrict__ Z, const unsigned short* __restrict__ Wt,
    const float* __restrict__ bias, unsigned short* __restrict__ Hout, int M) {
  __shared__ unsigned short smem[128 * 132];  // 33 KB; As+Bs (32 KB) then Cs
  unsigned short* As = smem;            // [128][64]
  unsigned short* Bs = smem + 8192;     // [128][64]
  const int n0 = blockIdx.x * 128;      // n fastest: 4 n-tiles of one m-tile adjacent
  const int m0 = blockIdx.y * 128;
  const int tid = threadIdx.x;
  const int lane = tid & 63;
  const int w = tid >> 6;
  const int wm = (w & 1) * 64;
  const int wn = (w >> 1) * 64;
  const int quad = lane >> 4;
  const int r16 = lane & 15;
  const int srow = lane >> 3;   // staging: row within 8-row chunk
  const int sslot = lane & 7;   // staging: 16B slot within row

  f32x4 acc[4][4];
#pragma unroll
  for (int i = 0; i < 4; ++i)
#pragma unroll
    for (int j = 0; j < 4; ++j)
      acc[i][j] = (f32x4){0.f, 0.f, 0.f, 0.f};

  for (int kt = 0; kt < 8; ++kt) {
    __syncthreads();
    const int kbase = kt * 64;
#pragma unroll
    for (int c = 0; c < 4; ++c) {
      int r0 = w * 32 + c * 8;
      int row = r0 + srow;
      int gk = kbase + (sslot ^ (row & 7)) * 8;   // swizzled source chunk
      int gm = m0 + row; if (gm > M - 1) gm = M - 1;  // clamp; garbage masked at store
      __builtin_amdgcn_global_load_lds(
          (AS1 void*)(void*)(Z + (size_t)gm * D + gk),
          (AS3 void*)(As + r0 * 64), 16, 0, 0);
      int gn = n0 + row;
      __builtin_amdgcn_global_load_lds(
          (AS1 void*)(void*)(Wt + (size_t)gn * D + gk),
          (AS3 void*)(Bs + r0 * 64), 16, 0, 0);
    }
    __syncthreads();

#pragma unroll
    for (int half = 0; half < 2; ++half) {
      bf16x8 a[4], b[4];
#pragma unroll
      for (int i = 0; i < 4; ++i) {
        int ra = wm + i * 16 + r16;
        a[i] = *(const bf16x8*)&As[ra * 64 + (((half << 2) + quad) ^ (ra & 7)) * 8];
        int rb = wn + i * 16 + r16;
        b[i] = *(const bf16x8*)&Bs[rb * 64 + (((half << 2) + quad) ^ (rb & 7)) * 8];
      }
#pragma unroll
      for (int i = 0; i < 4; ++i)
#pragma unroll
        for (int j = 0; j < 4; ++j)
          acc[i][j] = __builtin_amdgcn_mfma_f32_16x16x32_bf16(a[i], b[j], acc[i][j], 0, 0, 0);
    }
  }

  // ---- epilogue: bias+relu -> LDS (stride 132) -> coalesced full-line stores
  __syncthreads();
  unsigned short* Cs = smem;
#pragma unroll
  for (int j = 0; j < 4; ++j) {
    float bv = bias[n0 + wn + j * 16 + r16];
#pragma unroll
    for (int i = 0; i < 4; ++i) {
      int crow = wm + i * 16 + quad * 4;
      int ccol = wn + j * 16 + r16;
#pragma unroll
      for (int r = 0; r < 4; ++r) {
        float vv = acc[i][j][r] + bv;
        vv = vv > 0.f ? vv : 0.f;
        Cs[(crow + r) * 132 + ccol] = f2bf(vv);
      }
    }
  }
  __syncthreads();
#pragma unroll
  for (int it = 0; it < 8; ++it) {
    int row = w * 32 + it * 4 + (lane >> 4);
    int colofs = (lane & 15) * 8;
    int gm = m0 + row;
    if (gm < M) {
      ushort8v vv = *(const ushort8v*)&Cs[row * 132 + colofs];
      *(ushort8v*)&Hout[(size_t)gm * D + n0 + colofs] = vv;
    }
  }
}

// ---------------- classifier: out = h3 @ Wc + bc  (bf16 MFMA, no LDS) ----------------
__global__ __launch_bounds__(256) void cls_kernel(const unsigned short* __restrict__ hb,
    const unsigned short* __restrict__ Wct, const float* __restrict__ bc,
    float* __restrict__ out) {
  int w = threadIdx.x >> 6, lane = threadIdx.x & 63;
  int quad = lane >> 4, r16 = lane & 15;
  int nb = blockIdx.x * 64 + w * 16;
  int arow = nb + r16; if (arow > N_NODES - 1) arow = N_NODES - 1;
  f32x4 acc[3];
#pragma unroll
  for (int j = 0; j < 3; ++j) acc[j] = (f32x4){0.f, 0.f, 0.f, 0.f};
#pragma unroll 4
  for (int kt = 0; kt < 16; ++kt) {
    int kk = kt * 32 + quad * 8;
    bf16x8 a = *(const bf16x8*)&hb[(size_t)arow * D + kk];
#pragma unroll
    for (int j = 0; j < 3; ++j) {
      bf16x8 b = *(const bf16x8*)&Wct[(size_t)(j * 16 + r16) * D + kk];
      acc[j] = __builtin_amdgcn_mfma_f32_16x16x32_bf16(a, b, acc[j], 0, 0, 0);
    }
  }
#pragma unroll
  for (int j = 0; j < 3; ++j) {
    int gn = j * 16 + r16;
    if (gn < NCLS) {
      float bv = bc[gn];
#pragma unroll
      for (int r = 0; r < 4; ++r) {
        int gm = nb + quad * 4 + r;
        if (gm < N_NODES) out[(size_t)gm * NCLS + gn] = acc[j][r] + bv;
      }
    }
  }
}

extern "C" void kernel_launch(void* const* d_in, const int* in_sizes, int n_in,
                              void* d_out, int out_size, void* d_ws, size_t ws_size,
                              hipStream_t stream) {
  const float* feat = (const float*)d_in[0];
  const int* src = (const int*)d_in[1];
  const int* dst = (const int*)d_in[2];
  const float* W0 = (const float*)d_in[3];
  const float* b0 = (const float*)d_in[4];
  const float* W1 = (const float*)d_in[5];
  const float* b1 = (const float*)d_in[6];
  const float* W2 = (const float*)d_in[7];
  const float* b2 = (const float*)d_in[8];
  const float* Wc = (const float*)d_in[9];
  const float* bc = (const float*)d_in[10];
  float* out = (float*)d_out;

  char* ws = (char*)d_ws;
  size_t off = 0;
  auto alloc = [&](size_t bytes) {
    char* p = ws + off;
    off += (bytes + 255) & ~(size_t)255;
    return p;
  };
  unsigned short* hb = (unsigned short*)alloc((size_t)N_NODES * D * 2);   // 51.2 MB
  unsigned short* zb = (unsigned short*)alloc((size_t)N_NODES * D * 2);   // 51.2 MB
  unsigned short* Wt = (unsigned short*)alloc((size_t)3 * D * D * 2);     // 1.5 MB
  unsigned short* Wct = (unsigned short*)alloc((size_t)48 * D * 2);       // 49 KB
  int* row_ptr = (int*)alloc((size_t)(N_NODES + 1) * 4);
  int* counts  = (int*)alloc((size_t)N_NODES * 4);
  int* cursor  = (int*)alloc((size_t)N_NODES * 4);
  int* esrc    = (int*)alloc((size_t)N_EDGES * 4);
  int* bsum    = (int*)alloc((size_t)256 * 4);

  // CSR build
  hipMemsetAsync(counts, 0, (size_t)N_NODES * 4, stream);
  hist_kernel<<<(N_EDGES + 255) / 256, 256, 0, stream>>>(dst, counts);
  scan_local_kernel<<<SCAN_BLOCKS, 256, 0, stream>>>(counts, cursor, bsum);
  scan_bsum_kernel<<<1, 256, 0, stream>>>(bsum);
  scan_finish_kernel<<<SCAN_BLOCKS, 256, 0, stream>>>(counts, bsum, row_ptr, cursor);
  fill_kernel<<<(N_EDGES + 255) / 256, 256, 0, stream>>>(src, dst, cursor, esrc);

  cvt_feat_kernel<<<(N_NODES * D / 4 + 255) / 256, 256, 0, stream>>>(feat, hb);
  cvt_w3_kernel<<<3 * 262144 / 256, 256, 0, stream>>>(W0, W1, W2, Wt);
  cvt_wc_kernel<<<(48 * D + 255) / 256, 256, 0, stream>>>(Wc, Wct);

  dim3 ggrid(4, (N_NODES + 127) / 128);  // n-tiles fastest for Z-tile L2 reuse
  const float* bs[3] = {b0, b1, b2};
  for (int l = 0; l < 3; ++l) {
    agg_kernel<<<N_NODES / 4, 256, 0, stream>>>(hb, row_ptr, esrc, zb);
    gemm_kernel<<<ggrid, 256, 0, stream>>>(zb, Wt + (size_t)l * D * D, bs[l], hb, N_NODES);
  }
  cls_kernel<<<(N_NODES + 63) / 64, 256, 0, stream>>>(hb, Wct, bc, out);
}